// Round 11
// baseline (48.607 us; speedup 1.0000x reference)
//
#include <hip/hip_runtime.h>

#define BB 32
#define CC 16
#define HH 256
#define WW 256
#define HWSZ (HH * WW)

#define TW 32                  // tile width  -> 8-lane row = 128B full line stores
#define TH 8                   // tile height
#define CHB 8                  // channels per block (16 ch split across 2 blocks)
#define NBLK (BB * (WW/TW) * (HH/TH) * 2)   // 32*8*32*2 = 16384 blocks
#define NXCD 8

#define SROWS 14               // staged rows capacity (typ. need ~12)
#define SCOLS 43               // ODD row stride -> good bank phase spread
#define PLANE (SROWS * SCOLS)  // 602 floats per channel; x8ch x4B = 19.26 KB
#define MAXF4 10               // staged cols <= 40

typedef float f2 __attribute__((ext_vector_type(2)));
typedef float f4 __attribute__((ext_vector_type(4)));

__global__ __launch_bounds__(256, 8) void st_line_kernel(
    const float* __restrict__ input,   // [B,C,H,W]
    const float* __restrict__ theta,   // [B,6]
    float* __restrict__ out)           // [B,C,H,W]
{
    __shared__ float S[CHB * PLANE];   // 19.26 KB -> 8 blocks/CU

    // Chunked XCD swizzle (16384 % 8 == 0, bijective): adjacent tiles + the two
    // channel-halves of a tile stay on the same XCD (input L2 locality).
    int bid = blockIdx.x;
    int wg = (bid & (NXCD - 1)) * (NBLK / NXCD) + (bid >> 3);

    int b  = wg >> 9;              // 512 (tile,half) units per image
    int r  = wg & 511;             // [yt:5][xt:3][h:1]
    int yt = r >> 4;               // 0..31 y-tiles
    int xt = (r >> 1) & 7;         // 0..7  x-tiles
    int h  = r & 1;                // channel half

    int tid = threadIdx.x;
    int g   = tid >> 6;            // wave id 0..3 -> local channels 2g, 2g+1
    int l   = tid & 63;
    int row = l >> 3;              // 0..7 row in tile
    int xq  = l & 7;               // 0..7 col-quad -> lanes 0..7 = one 128B line
    int oy  = yt * TH + row;
    int ox0 = xt * TW + xq * 4;    // 4 consecutive x-pixels (f4 store)

    const float* th = theta + b * 6;
    float t0 = th[0], t1 = th[1], t2 = th[2];
    float t3 = th[3], t4 = th[4], t5 = th[5];

    const float step = 2.0f / 255.0f;

    // ---- staging window from tile-corner bounds (affine + monotone clip) ----
    float gxa = -1.0f + (xt * TW) * step;
    float gxb = -1.0f + (xt * TW + TW - 1) * step;
    float gya = -1.0f + (yt * TH) * step;
    float gyb = -1.0f + (yt * TH + TH - 1) * step;

    float x00 = t0 * gxa + t1 * gya + t2, x01 = t0 * gxa + t1 * gyb + t2;
    float x10 = t0 * gxb + t1 * gya + t2, x11 = t0 * gxb + t1 * gyb + t2;
    float y00 = t3 * gxa + t4 * gya + t5, y01 = t3 * gxa + t4 * gyb + t5;
    float y10 = t3 * gxb + t4 * gya + t5, y11 = t3 * gxb + t4 * gyb + t5;

    float xmn = fminf(fminf(x00, x01), fminf(x10, x11));
    float xmx = fmaxf(fmaxf(x00, x01), fmaxf(x10, x11));
    float ymn = fminf(fminf(y00, y01), fminf(y10, y11));
    float ymx = fmaxf(fmaxf(y00, y01), fmaxf(y10, y11));
    xmn = fminf(fmaxf(xmn, -1.0f), 1.0f);
    xmx = fminf(fmaxf(xmx, -1.0f), 1.0f);
    ymn = fminf(fmaxf(ymn, -1.0f), 1.0f);
    ymx = fminf(fmaxf(ymx, -1.0f), 1.0f);
    // +-0.01 px guard absorbs fp-associativity between corner-bound and
    // per-pixel evaluations (error ~1e-4 px).
    float pxmn = (xmn + 1.0f) * 127.5f - 0.01f, pxmx = (xmx + 1.0f) * 127.5f + 0.01f;
    float pymn = (ymn + 1.0f) * 127.5f - 0.01f, pymx = (ymx + 1.0f) * 127.5f + 0.01f;

    int cx0 = (int)floorf(pxmn);
    cx0 = (max(0, min(cx0, WW - 4))) & ~3;              // 16B-aligned global start
    int cxend = min((int)floorf(pxmx) + 1, WW - 1);     // inclusive last col needed
    int wf4 = (cxend - cx0 + 4) >> 2;
    wf4 = min(wf4, min(MAXF4, (WW - cx0) >> 2));
    int wcols = wf4 * 4;

    int ry0 = (int)floorf(pymn);
    ry0 = max(0, min(ry0, HH - 1));
    int ryend = min((int)floorf(pymx) + 1, HH - 1);
    int rows = min(min(ryend - ry0 + 1, SROWS), HH - ry0);

    // ---- staging slot: div-free 16x16 mapping ----
    int rr = tid >> 4;             // 0..15 (>= SROWS covers all rows)
    int cq = tid & 15;
    bool valid = (rr < rows) && (cq < wf4);
    int sgoff = rr * WW + cq * 4;      // global float offset within window
    int sloff = rr * SCOLS + cq * 4;   // LDS float offset

    // ---- per-pixel offsets & weights (channel-invariant) ----
    int   off[4], goff[4];
    float w00[4], w01[4], w10[4], w11[4];
    bool  ok[4];
    float gy = -1.0f + oy * step;
    float cxp = t1 * gy + t2;
    float cyp = t4 * gy + t5;

    #pragma unroll
    for (int j = 0; j < 4; ++j) {
        float gx = -1.0f + (ox0 + j) * step;
        float xs = fminf(fmaxf(t0 * gx + cxp, -1.0f), 1.0f);
        float ys = fminf(fmaxf(t3 * gx + cyp, -1.0f), 1.0f);
        float x = (xs + 1.0f) * 127.5f;
        float y = (ys + 1.0f) * 127.5f;
        // bx=min(floor(x),254), fx=x-bx in [0,1]: exact index-clamp semantics
        float bxf = fminf(floorf(x), 254.0f);
        float byf = fminf(floorf(y), 254.0f);
        float fx = x - bxf, fy = y - byf;
        int bx = (int)bxf, by = (int)byf;

        w00[j] = (1.0f - fx) * (1.0f - fy);
        w01[j] = fx * (1.0f - fy);
        w10[j] = (1.0f - fx) * fy;
        w11[j] = fx * fy;

        int lx = bx - cx0, ly = by - ry0;
        ok[j] = (lx >= 0) && (lx <= wcols - 2) && (ly >= 0) && (ly <= rows - 2);
        off[j]  = ly * SCOLS + lx;
        goff[j] = by * WW + bx;
    }

    const float* ibase = input + (size_t)b * CC * HWSZ + (size_t)h * CHB * HWSZ;
    float* obase = out + (size_t)b * CC * HWSZ + (size_t)h * CHB * HWSZ
                       + (size_t)oy * WW + ox0;

    // ---- stage this half's 8 channels, ONE barrier total ----
    f4 rb[CHB];
    const float* wsrc = ibase + ry0 * WW + cx0;
    #pragma unroll
    for (int ch = 0; ch < CHB; ++ch) {
        if (valid) rb[ch] = *(const f4*)(wsrc + ch * HWSZ + sgoff);
    }
    #pragma unroll
    for (int ch = 0; ch < CHB; ++ch) {
        if (valid) {
            float* d = &S[ch * PLANE + sloff];
            d[0] = rb[ch].x;
            d[1] = rb[ch].y;
            d[2] = rb[ch].z;
            d[3] = rb[ch].w;
        }
    }
    __syncthreads();                   // the ONLY barrier

    // ---- gather + blend 2 channels x 4 px from LDS; no further sync ----
    #pragma unroll
    for (int u = 0; u < 2; ++u) {
        int c = g * 2 + u;             // local channel 0..7
        const float* Sc = &S[c * PLANE];
        const float* p  = ibase + c * HWSZ;
        f4 ov;
        #pragma unroll
        for (int j = 0; j < 4; ++j) {
            float v00, v01, v10, v11;
            if (ok[j]) {
                v00 = Sc[off[j]];              // ds_read2_b32 {0,1}
                v01 = Sc[off[j] + 1];
                v10 = Sc[off[j] + SCOLS];      // ds_read2_b32 {43,44}
                v11 = Sc[off[j] + SCOLS + 1];
            } else {
                f2 a, bb;   // exact global fallback (rare, per-pixel)
                __builtin_memcpy(&a,  p + goff[j], 8);
                __builtin_memcpy(&bb, p + goff[j] + WW, 8);
                v00 = a.x; v01 = a.y; v10 = bb.x; v11 = bb.y;
            }
            ov[j] = v00 * w00[j] + v01 * w01[j] + v10 * w10[j] + v11 * w11[j];
        }
        // NT store is safe again: lanes 0..7 of each row = one FULL 128B line.
        __builtin_nontemporal_store(ov, (f4*)(obase + c * HWSZ));
    }
}

extern "C" void kernel_launch(void* const* d_in, const int* in_sizes, int n_in,
                              void* d_out, int out_size, void* d_ws, size_t ws_size,
                              hipStream_t stream) {
    const float* input = (const float*)d_in[0];
    const float* theta = (const float*)d_in[1];
    float* out = (float*)d_out;

    dim3 block(256);
    dim3 grid(NBLK);   // 16384 blocks
    hipLaunchKernelGGL(st_line_kernel, grid, block, 0, stream,
                       input, theta, out);
}

// Round 12
// 47.993 us; speedup vs baseline: 1.0128x; 1.0128x over previous
//
#include <hip/hip_runtime.h>

#define BB 32
#define CC 16
#define HH 256
#define WW 256
#define HWSZ (HH * WW)

#define TW 32                  // tile width  -> 8-lane row = one full 128B line store
#define TH 8                   // tile height
#define CHB 8                  // channels per block (16 ch split across 2 blocks)
#define NBLK (BB * (WW/TW) * (HH/TH) * 2)   // 32*8*32*2 = 16384 blocks
#define NXCD 8

#define SROWS 14               // staged rows capacity (typ. need ~12)
#define SCOLS 43               // ODD row stride -> 2-way bank spread for stride-4 lanes
#define PLANE (SROWS * SCOLS)  // 602 floats per channel; x8ch x4B = 19.26 KB
#define MAXF4 10               // staged cols <= 40

typedef float f2 __attribute__((ext_vector_type(2)));
typedef float f4 __attribute__((ext_vector_type(4)));

__global__ __launch_bounds__(256, 8) void st_merge_kernel(
    const float* __restrict__ input,   // [B,C,H,W]
    const float* __restrict__ theta,   // [B,6]
    float* __restrict__ out)           // [B,C,H,W]
{
    __shared__ float S[CHB * PLANE];   // 19.26 KB -> 8 blocks/CU

    // Chunked XCD swizzle (16384 % 8 == 0, bijective): adjacent tiles + the two
    // channel-halves of a tile stay on the same XCD (input L2 locality).
    int bid = blockIdx.x;
    int wg = (bid & (NXCD - 1)) * (NBLK / NXCD) + (bid >> 3);

    int b  = wg >> 9;              // 512 (tile,half) units per image
    int r  = wg & 511;             // [yt:5][xt:3][h:1]
    int yt = r >> 4;               // 0..31 y-tiles
    int xt = (r >> 1) & 7;         // 0..7  x-tiles
    int h  = r & 1;                // channel half

    int tid = threadIdx.x;
    int g   = tid >> 6;            // wave id 0..3 -> local channels 2g, 2g+1
    int l   = tid & 63;
    int row = l >> 3;              // 0..7 row in tile
    int xq  = l & 7;               // 0..7 col-quad -> 8 lanes = one 128B line
    int oy  = yt * TH + row;
    int ox0 = xt * TW + xq * 4;    // 4 consecutive x-pixels (f4 store)

    const float* th = theta + b * 6;
    float t0 = th[0], t1 = th[1], t2 = th[2];
    float t3 = th[3], t4 = th[4], t5 = th[5];

    const float step = 2.0f / 255.0f;

    // ---- staging window from tile-corner bounds (affine + monotone clip) ----
    float gxa = -1.0f + (xt * TW) * step;
    float gxb = -1.0f + (xt * TW + TW - 1) * step;
    float gya = -1.0f + (yt * TH) * step;
    float gyb = -1.0f + (yt * TH + TH - 1) * step;

    float x00 = t0 * gxa + t1 * gya + t2, x01 = t0 * gxa + t1 * gyb + t2;
    float x10 = t0 * gxb + t1 * gya + t2, x11 = t0 * gxb + t1 * gyb + t2;
    float y00 = t3 * gxa + t4 * gya + t5, y01 = t3 * gxa + t4 * gyb + t5;
    float y10 = t3 * gxb + t4 * gya + t5, y11 = t3 * gxb + t4 * gyb + t5;

    float xmn = fminf(fminf(x00, x01), fminf(x10, x11));
    float xmx = fmaxf(fmaxf(x00, x01), fmaxf(x10, x11));
    float ymn = fminf(fminf(y00, y01), fminf(y10, y11));
    float ymx = fmaxf(fmaxf(y00, y01), fmaxf(y10, y11));
    xmn = fminf(fmaxf(xmn, -1.0f), 1.0f);
    xmx = fminf(fmaxf(xmx, -1.0f), 1.0f);
    ymn = fminf(fmaxf(ymn, -1.0f), 1.0f);
    ymx = fminf(fmaxf(ymx, -1.0f), 1.0f);
    // +-0.01 px guard absorbs fp-associativity between corner-bound and
    // per-pixel evaluations (error ~1e-4 px).
    float pxmn = (xmn + 1.0f) * 127.5f - 0.01f, pxmx = (xmx + 1.0f) * 127.5f + 0.01f;
    float pymn = (ymn + 1.0f) * 127.5f - 0.01f, pymx = (ymx + 1.0f) * 127.5f + 0.01f;

    int cx0 = (int)floorf(pxmn);
    cx0 = (max(0, min(cx0, WW - 4))) & ~3;              // 16B-aligned global start
    int cxend = min((int)floorf(pxmx) + 1, WW - 1);     // inclusive last col needed
    int wf4 = (cxend - cx0 + 4) >> 2;
    wf4 = min(wf4, min(MAXF4, (WW - cx0) >> 2));
    int wcols = wf4 * 4;

    int ry0 = (int)floorf(pymn);
    ry0 = max(0, min(ry0, HH - 1));
    int ryend = min((int)floorf(pymx) + 1, HH - 1);
    int rows = min(min(ryend - ry0 + 1, SROWS), HH - ry0);
    int nf4 = rows * wf4;                               // <= 14*10 = 140 < 256

    // ---- staging slot: DENSE mapping (one div, amortized over 8 channels).
    // Threads 0..nf4-1 are fully active; tail waves execz-skip -> every
    // staging VMEM instruction moves full 64-lane payloads (R10 vs R11 lesson).
    bool valid = tid < nf4;
    int rr = tid / wf4;
    int cq = tid - rr * wf4;
    int sgoff = rr * WW + cq * 4;      // global float offset within window
    int sloff = rr * SCOLS + cq * 4;   // LDS float offset

    // ---- per-pixel offsets & weights (channel-invariant) ----
    int   off[4], goff[4];
    float w00[4], w01[4], w10[4], w11[4];
    bool  ok[4];
    float gy = -1.0f + oy * step;
    float cxp = t1 * gy + t2;
    float cyp = t4 * gy + t5;

    #pragma unroll
    for (int j = 0; j < 4; ++j) {
        float gx = -1.0f + (ox0 + j) * step;
        float xs = fminf(fmaxf(t0 * gx + cxp, -1.0f), 1.0f);
        float ys = fminf(fmaxf(t3 * gx + cyp, -1.0f), 1.0f);
        float x = (xs + 1.0f) * 127.5f;
        float y = (ys + 1.0f) * 127.5f;
        // bx=min(floor(x),254), fx=x-bx in [0,1]: exact index-clamp semantics
        float bxf = fminf(floorf(x), 254.0f);
        float byf = fminf(floorf(y), 254.0f);
        float fx = x - bxf, fy = y - byf;
        int bx = (int)bxf, by = (int)byf;

        w00[j] = (1.0f - fx) * (1.0f - fy);
        w01[j] = fx * (1.0f - fy);
        w10[j] = (1.0f - fx) * fy;
        w11[j] = fx * fy;

        int lx = bx - cx0, ly = by - ry0;
        ok[j] = (lx >= 0) && (lx <= wcols - 2) && (ly >= 0) && (ly <= rows - 2);
        off[j]  = ly * SCOLS + lx;
        goff[j] = by * WW + bx;
    }

    const float* ibase = input + (size_t)b * CC * HWSZ + (size_t)h * CHB * HWSZ;
    float* obase = out + (size_t)b * CC * HWSZ + (size_t)h * CHB * HWSZ
                       + (size_t)oy * WW + ox0;

    // ---- stage this half's 8 channels, ONE barrier total ----
    f4 rb[CHB];
    const float* wsrc = ibase + ry0 * WW + cx0;
    #pragma unroll
    for (int ch = 0; ch < CHB; ++ch) {
        if (valid) rb[ch] = *(const f4*)(wsrc + ch * HWSZ + sgoff);
    }
    #pragma unroll
    for (int ch = 0; ch < CHB; ++ch) {
        if (valid) {
            float* d = &S[ch * PLANE + sloff];
            d[0] = rb[ch].x;
            d[1] = rb[ch].y;
            d[2] = rb[ch].z;
            d[3] = rb[ch].w;
        }
    }
    __syncthreads();                   // the ONLY barrier

    // ---- gather + blend 2 channels x 4 px from LDS; no further sync ----
    #pragma unroll
    for (int u = 0; u < 2; ++u) {
        int c = g * 2 + u;             // local channel 0..7
        const float* Sc = &S[c * PLANE];
        const float* p  = ibase + c * HWSZ;
        f4 ov;
        #pragma unroll
        for (int j = 0; j < 4; ++j) {
            float v00, v01, v10, v11;
            if (ok[j]) {
                v00 = Sc[off[j]];              // ds_read2_b32 {0,1}
                v01 = Sc[off[j] + 1];
                v10 = Sc[off[j] + SCOLS];      // ds_read2_b32 {43,44}
                v11 = Sc[off[j] + SCOLS + 1];
            } else {
                f2 a, bb;   // exact global fallback (rare, per-pixel)
                __builtin_memcpy(&a,  p + goff[j], 8);
                __builtin_memcpy(&bb, p + goff[j] + WW, 8);
                v00 = a.x; v01 = a.y; v10 = bb.x; v11 = bb.y;
            }
            ov[j] = v00 * w00[j] + v01 * w01[j] + v10 * w10[j] + v11 * w11[j];
        }
        // PLAIN full-line store (R9/R10 lesson: plain beat NT on timed replays).
        *(f4*)(obase + c * HWSZ) = ov;
    }
}

extern "C" void kernel_launch(void* const* d_in, const int* in_sizes, int n_in,
                              void* d_out, int out_size, void* d_ws, size_t ws_size,
                              hipStream_t stream) {
    const float* input = (const float*)d_in[0];
    const float* theta = (const float*)d_in[1];
    float* out = (float*)d_out;

    dim3 block(256);
    dim3 grid(NBLK);   // 16384 blocks
    hipLaunchKernelGGL(st_merge_kernel, grid, block, 0, stream,
                       input, theta, out);
}

// Round 13
// 45.796 us; speedup vs baseline: 1.0614x; 1.0480x over previous
//
#include <hip/hip_runtime.h>

#define BB 32
#define CC 16
#define HH 256
#define WW 256
#define HWSZ (HH * WW)

#define TW 16                  // tile width
#define TH 16                  // tile height
#define CHB 8                  // channels per block (16 ch split across 2 blocks)
#define NBLK (BB * (WW/TW) * (HH/TH) * 2)   // 16384 blocks
#define NXCD 8

#define SROWS 23               // staged rows capacity
#define SCOLS 27               // ODD row stride -> stride-4 gather lanes spread ~2-way
#define PLANE (SROWS * SCOLS)  // 621 floats per channel
#define MAXF4 6                // staged cols <= 24

typedef float f2 __attribute__((ext_vector_type(2)));
typedef float f4 __attribute__((ext_vector_type(4)));

__global__ __launch_bounds__(256, 8) void st_final_kernel(
    const float* __restrict__ input,   // [B,C,H,W]
    const float* __restrict__ theta,   // [B,6]
    float* __restrict__ out)           // [B,C,H,W]
{
    __shared__ float S[CHB * PLANE];   // 19.9 KB -> 8 blocks/CU (100% occ cap)

    // Chunked XCD swizzle (16384 % 8 == 0, bijective). Adjacent tiles (and the
    // two channel-halves of one tile) stay on the same XCD -> their half-line
    // output stores merge in that XCD's L2 (plain stores, NOT nontemporal).
    int bid = blockIdx.x;
    int wg = (bid & (NXCD - 1)) * (NBLK / NXCD) + (bid >> 3);

    int b  = wg >> 9;              // 512 (tile,half) units per image
    int r  = wg & 511;
    int yt = r >> 5;               // 16 y-tiles
    int xt = (r >> 1) & 15;        // 16 x-tiles
    int h  = r & 1;                // channel half: channels h*8 .. h*8+7

    int tid = threadIdx.x;
    int g   = tid >> 6;            // wave id 0..3 -> local channels 2g, 2g+1
    int l   = tid & 63;
    int row = l >> 2;              // 0..15 row in tile
    int xq  = l & 3;               // 0..3 col-quad
    int oy  = yt * TH + row;
    int ox0 = xt * TW + xq * 4;    // 4 consecutive x-pixels (f4 store)

    const float* th = theta + b * 6;
    float t0 = th[0], t1 = th[1], t2 = th[2];
    float t3 = th[3], t4 = th[4], t5 = th[5];

    const float step = 2.0f / 255.0f;

    // ---- staging window from tile-corner bounds (affine + monotone clip) ----
    float gxa = -1.0f + (xt * TW) * step;
    float gxb = -1.0f + (xt * TW + TW - 1) * step;
    float gya = -1.0f + (yt * TH) * step;
    float gyb = -1.0f + (yt * TH + TH - 1) * step;

    float x00 = t0 * gxa + t1 * gya + t2, x01 = t0 * gxa + t1 * gyb + t2;
    float x10 = t0 * gxb + t1 * gya + t2, x11 = t0 * gxb + t1 * gyb + t2;
    float y00 = t3 * gxa + t4 * gya + t5, y01 = t3 * gxa + t4 * gyb + t5;
    float y10 = t3 * gxb + t4 * gya + t5, y11 = t3 * gxb + t4 * gyb + t5;

    float xmn = fminf(fminf(x00, x01), fminf(x10, x11));
    float xmx = fmaxf(fmaxf(x00, x01), fmaxf(x10, x11));
    float ymn = fminf(fminf(y00, y01), fminf(y10, y11));
    float ymx = fmaxf(fmaxf(y00, y01), fmaxf(y10, y11));
    xmn = fminf(fmaxf(xmn, -1.0f), 1.0f);
    xmx = fminf(fmaxf(xmx, -1.0f), 1.0f);
    ymn = fminf(fmaxf(ymn, -1.0f), 1.0f);
    ymx = fminf(fmaxf(ymx, -1.0f), 1.0f);
    float pxmn = (xmn + 1.0f) * 127.5f, pxmx = (xmx + 1.0f) * 127.5f;
    float pymn = (ymn + 1.0f) * 127.5f, pymx = (ymx + 1.0f) * 127.5f;

    int cx0 = (int)floorf(pxmn) - 1;
    cx0 = (max(0, min(cx0, WW - 4))) & ~3;              // 16B-aligned global start
    int cxend = min((int)floorf(pxmx) + 2, WW - 1);     // inclusive
    int wf4 = (cxend - cx0 + 4) >> 2;
    wf4 = min(wf4, min(MAXF4, (WW - cx0) >> 2));
    int wcols = wf4 * 4;

    int ry0 = (int)floorf(pymn) - 1;
    ry0 = max(0, min(ry0, HH - 1));
    int ryend = min((int)floorf(pymx) + 2, HH - 1);
    int rows = min(min(ryend - ry0 + 1, SROWS), HH - ry0);
    int nf4 = rows * wf4;                               // <= 23*6 = 138 < 256

    // ---- staging slot: DENSE mapping (one div, amortized over 8 channels) ----
    bool valid = tid < nf4;
    int rr = tid / wf4;
    int cq = tid - rr * wf4;
    int sgoff = rr * WW + cq * 4;      // global float offset within window
    int sloff = rr * SCOLS + cq * 4;   // LDS float offset (scalar writes)

    // ---- per-pixel offsets & weights (channel-invariant) ----
    int   off[4], goff[4];
    float w00[4], w01[4], w10[4], w11[4];
    bool  ok[4];
    float gy = -1.0f + oy * step;
    float cxp = t1 * gy + t2;
    float cyp = t4 * gy + t5;

    #pragma unroll
    for (int j = 0; j < 4; ++j) {
        float gx = -1.0f + (ox0 + j) * step;
        float xs = fminf(fmaxf(t0 * gx + cxp, -1.0f), 1.0f);
        float ys = fminf(fmaxf(t3 * gx + cyp, -1.0f), 1.0f);
        float x = (xs + 1.0f) * 127.5f;
        float y = (ys + 1.0f) * 127.5f;
        // bx=min(floor(x),254), fx=x-bx in [0,1]: exact index-clamp semantics
        float bxf = fminf(floorf(x), 254.0f);
        float byf = fminf(floorf(y), 254.0f);
        float fx = x - bxf, fy = y - byf;
        int bx = (int)bxf, by = (int)byf;

        w00[j] = (1.0f - fx) * (1.0f - fy);
        w01[j] = fx * (1.0f - fy);
        w10[j] = (1.0f - fx) * fy;
        w11[j] = fx * fy;

        int lx = bx - cx0, ly = by - ry0;
        ok[j] = (lx >= 0) && (lx <= wcols - 2) && (ly >= 0) && (ly <= rows - 2);
        off[j]  = ly * SCOLS + lx;
        goff[j] = by * WW + bx;
    }

    const float* ibase = input + (size_t)b * CC * HWSZ + (size_t)h * CHB * HWSZ;
    float* obase = out + (size_t)b * CC * HWSZ + (size_t)h * CHB * HWSZ
                       + (size_t)oy * WW + ox0;

    // ---- stage this half's 8 channels, ONE barrier total ----
    f4 rb[CHB];
    const float* wsrc = ibase + ry0 * WW + cx0;
    #pragma unroll
    for (int ch = 0; ch < CHB; ++ch) {
        if (valid) rb[ch] = *(const f4*)(wsrc + ch * HWSZ + sgoff);
    }
    #pragma unroll
    for (int ch = 0; ch < CHB; ++ch) {
        if (valid) {
            float* d = &S[ch * PLANE + sloff];
            d[0] = rb[ch].x;           // ds_write2_b32 pairs (one-time)
            d[1] = rb[ch].y;
            d[2] = rb[ch].z;
            d[3] = rb[ch].w;
        }
    }
    __syncthreads();                   // the ONLY barrier

    // ---- gather + blend 2 channels x 4 px from LDS; no further sync ----
    #pragma unroll
    for (int u = 0; u < 2; ++u) {
        int c = g * 2 + u;             // local channel 0..7
        const float* Sc = &S[c * PLANE];
        const float* p  = ibase + c * HWSZ;
        f4 ov;
        #pragma unroll
        for (int j = 0; j < 4; ++j) {
            float v00, v01, v10, v11;
            if (ok[j]) {
                v00 = Sc[off[j]];              // ds_read2_b32 {0,1}
                v01 = Sc[off[j] + 1];
                v10 = Sc[off[j] + SCOLS];      // ds_read2_b32 {27,28}
                v11 = Sc[off[j] + SCOLS + 1];
            } else {
                f2 a, bb;   // exact global fallback (rare, per-pixel)
                __builtin_memcpy(&a,  p + goff[j], 8);
                __builtin_memcpy(&bb, p + goff[j] + WW, 8);
                v00 = a.x; v01 = a.y; v10 = bb.x; v11 = bb.y;
            }
            ov[j] = v00 * w00[j] + v01 * w01[j] + v10 * w10[j] + v11 * w11[j];
        }
        // PLAIN store: half-lines from adjacent tiles merge in L2.
        *(f4*)(obase + c * HWSZ) = ov;
    }
}

extern "C" void kernel_launch(void* const* d_in, const int* in_sizes, int n_in,
                              void* d_out, int out_size, void* d_ws, size_t ws_size,
                              hipStream_t stream) {
    const float* input = (const float*)d_in[0];
    const float* theta = (const float*)d_in[1];
    float* out = (float*)d_out;

    dim3 block(256);
    dim3 grid(NBLK);   // 16384 blocks
    hipLaunchKernelGGL(st_final_kernel, grid, block, 0, stream,
                       input, theta, out);
}